// Round 1
// baseline (861.123 us; speedup 1.0000x reference)
//
#include <hip/hip_runtime.h>

#define N_NODES 50000
#define N_EDGES 800000
#define ET (N_EDGES + N_NODES)   // 850000 incl. self loops
#define HEADS 8

// ---------- edge-index layout detection (int32 vs int64 storage) ----------
__global__ void k_detect(const int* __restrict__ ei, int* __restrict__ flag){
  if (blockIdx.x == 0 && threadIdx.x == 0){
    int zeros = 0;
    for (int i = 0; i < 64; i++){
      if (ei[2*i + 1] == 0) zeros++;
    }
    *flag = (zeros >= 60) ? 1 : 0;   // 1 => int64 little-endian layout
  }
}

__device__ __forceinline__ int edge_src(const int* ei, int e, int is64){
  if (e >= N_EDGES) return e - N_EDGES;          // self loop
  return is64 ? ei[2*e] : ei[e];
}
__device__ __forceinline__ int edge_dst(const int* ei, int e, int is64){
  if (e >= N_EDGES) return e - N_EDGES;          // self loop
  return is64 ? ei[2*(N_EDGES + e)] : ei[N_EDGES + e];
}

// ---------------- CSR build ----------------
__global__ void k_zero2(int* __restrict__ a, int* __restrict__ b, int n){
  int i = blockIdx.x*blockDim.x + threadIdx.x;
  if (i < n){ a[i] = 0; b[i] = 0; }
}

__global__ void k_degree(const int* __restrict__ ei, int* __restrict__ deg,
                         const int* __restrict__ flag){
  int e = blockIdx.x*blockDim.x + threadIdx.x;
  if (e >= ET) return;
  int is64 = *flag;
  int d = edge_dst(ei, e, is64);
  atomicAdd(&deg[d], 1);
}

__global__ void k_scan(const int* __restrict__ deg, int* __restrict__ row_ptr){
  __shared__ int lds[1024];
  __shared__ int carry_s;
  if (threadIdx.x == 0) carry_s = 0;
  __syncthreads();
  for (int base = 0; base < N_NODES; base += 1024){
    int i = base + threadIdx.x;
    int v = (i < N_NODES) ? deg[i] : 0;
    lds[threadIdx.x] = v;
    __syncthreads();
    for (int off = 1; off < 1024; off <<= 1){
      int t = (threadIdx.x >= off) ? lds[threadIdx.x - off] : 0;
      __syncthreads();
      lds[threadIdx.x] += t;
      __syncthreads();
    }
    int carry = carry_s;
    if (i < N_NODES) row_ptr[i] = carry + lds[threadIdx.x] - v;  // exclusive
    __syncthreads();
    if (threadIdx.x == 1023) carry_s = carry + lds[1023];
    __syncthreads();
  }
  if (threadIdx.x == 0) row_ptr[N_NODES] = carry_s;
}

__global__ void k_fill(const int* __restrict__ ei, const int* __restrict__ row_ptr,
                       int* __restrict__ cnt, int* __restrict__ col,
                       const int* __restrict__ flag){
  int e = blockIdx.x*blockDim.x + threadIdx.x;
  if (e >= ET) return;
  int is64 = *flag;
  int s = edge_src(ei, e, is64);
  int d = edge_dst(ei, e, is64);
  int pos = atomicAdd(&cnt[d], 1);
  col[row_ptr[d] + pos] = s;
}

// ---------------- layer 1: GEMM [N,128]x[128,128] + alpha_src/dst ----------------
__global__ void k_gemm_alpha1(const float* __restrict__ x, const float* __restrict__ W,
                              const float* __restrict__ asv, const float* __restrict__ adv,
                              float* __restrict__ h, float* __restrict__ als,
                              float* __restrict__ ald){
  __shared__ float xs[8][128];
  int c = threadIdx.x;           // 0..127 (output column)
  int n0 = blockIdx.x * 8;
  #pragma unroll
  for (int i = 0; i < 8; i++){
    int n = n0 + i;
    xs[i][c] = (n < N_NODES) ? x[n*128 + c] : 0.f;
  }
  __syncthreads();
  float acc[8] = {0.f,0.f,0.f,0.f,0.f,0.f,0.f,0.f};
  for (int k = 0; k < 128; k++){
    float w = W[k*128 + c];
    #pragma unroll
    for (int i = 0; i < 8; i++) acc[i] += xs[i][k] * w;
  }
  float a_s = asv[c], a_d = adv[c];   // flat [8,16] -> index c
  #pragma unroll
  for (int i = 0; i < 8; i++){
    int n = n0 + i;
    if (n >= N_NODES) break;          // block-uniform
    h[n*128 + c] = acc[i];
    float vs = acc[i] * a_s;
    float vd = acc[i] * a_d;
    #pragma unroll
    for (int off = 1; off < 16; off <<= 1){
      vs += __shfl_xor(vs, off, 64);
      vd += __shfl_xor(vd, off, 64);
    }
    if ((c & 15) == 0){
      als[n*8 + (c >> 4)] = vs;
      ald[n*8 + (c >> 4)] = vd;
    }
  }
}

// ---------------- layer 2: GEMM [N,128]x[128,512] + alpha_src/dst ----------------
__global__ void k_gemm_alpha2(const float* __restrict__ x, const float* __restrict__ W,
                              const float* __restrict__ asv, const float* __restrict__ adv,
                              float* __restrict__ h, float* __restrict__ als,
                              float* __restrict__ ald){
  __shared__ float xs[8][128];
  int c = threadIdx.x;           // 0..511
  int n0 = blockIdx.x * 8;
  for (int idx = c; idx < 1024; idx += 512){
    int i = idx >> 7, k = idx & 127;
    int n = n0 + i;
    xs[i][k] = (n < N_NODES) ? x[n*128 + k] : 0.f;
  }
  __syncthreads();
  float acc[8] = {0.f,0.f,0.f,0.f,0.f,0.f,0.f,0.f};
  for (int k = 0; k < 128; k++){
    float w = W[k*512 + c];
    #pragma unroll
    for (int i = 0; i < 8; i++) acc[i] += xs[i][k] * w;
  }
  float a_s = asv[c], a_d = adv[c];   // flat [8,64] -> index c
  #pragma unroll
  for (int i = 0; i < 8; i++){
    int n = n0 + i;
    if (n >= N_NODES) break;          // block-uniform
    h[(size_t)n*512 + c] = acc[i];
    float vs = acc[i] * a_s;
    float vd = acc[i] * a_d;
    #pragma unroll
    for (int off = 1; off < 64; off <<= 1){
      vs += __shfl_xor(vs, off, 64);
      vd += __shfl_xor(vd, off, 64);
    }
    if ((c & 63) == 0){
      als[n*8 + (c >> 6)] = vs;
      ald[n*8 + (c >> 6)] = vd;
    }
  }
}

// ---------------- edge softmax weights (one wave per dst node) ----------------
__global__ void k_attn(const float* __restrict__ als, const float* __restrict__ ald,
                       const int* __restrict__ row_ptr, const int* __restrict__ col,
                       float* __restrict__ ew){
  int gid = blockIdx.x*blockDim.x + threadIdx.x;
  int n = gid >> 6;
  int lane = threadIdx.x & 63;
  if (n >= N_NODES) return;
  int beg = row_ptr[n], end = row_ptr[n+1];
  int items = (end - beg) * 8;        // (edge, head) pairs
  int h = lane & 7;                   // fixed head class per lane (stride 64 ≡ 0 mod 8)
  float ad = ald[n*8 + h];
  // pass 1: per-head max
  float m = -1e30f;
  for (int it = lane; it < items; it += 64){
    int s = col[beg + (it >> 3)];
    float a = als[s*8 + h] + ad;
    float e = (a > 0.f) ? a : 0.2f*a;
    m = fmaxf(m, e);
  }
  m = fmaxf(m, __shfl_xor(m, 8, 64));
  m = fmaxf(m, __shfl_xor(m, 16, 64));
  m = fmaxf(m, __shfl_xor(m, 32, 64));
  // pass 2: per-head denom
  float den = 0.f;
  for (int it = lane; it < items; it += 64){
    int s = col[beg + (it >> 3)];
    float a = als[s*8 + h] + ad;
    float e = (a > 0.f) ? a : 0.2f*a;
    den += __expf(e - m);
  }
  den += __shfl_xor(den, 8, 64);
  den += __shfl_xor(den, 16, 64);
  den += __shfl_xor(den, 32, 64);
  float inv = 1.f / (den + 1e-16f);
  // pass 3: normalized weights in CSR order
  for (int it = lane; it < items; it += 64){
    int j = beg + (it >> 3);
    int s = col[j];
    float a = als[s*8 + h] + ad;
    float e = (a > 0.f) ? a : 0.2f*a;
    ew[(size_t)j*8 + h] = __expf(e - m) * inv;
  }
}

// ---------------- layer-1 aggregation: concat heads, +b1, relu ----------------
__global__ void k_agg1(const float* __restrict__ h, const float* __restrict__ ew,
                       const int* __restrict__ row_ptr, const int* __restrict__ col,
                       const float* __restrict__ bias, float* __restrict__ outp){
  int gid = blockIdx.x*blockDim.x + threadIdx.x;
  int n = gid >> 6;
  int lane = threadIdx.x & 63;
  if (n >= N_NODES) return;
  int beg = row_ptr[n], end = row_ptr[n+1];
  int c0 = lane, c1 = lane + 64;
  int h0 = c0 >> 4, h1c = c1 >> 4;
  float acc0 = 0.f, acc1 = 0.f;
  for (int j = beg; j < end; j++){
    int s = col[j];
    float w0 = ew[(size_t)j*8 + h0];
    float w1 = ew[(size_t)j*8 + h1c];
    acc0 += w0 * h[s*128 + c0];
    acc1 += w1 * h[s*128 + c1];
  }
  float o0 = acc0 + bias[c0];
  float o1 = acc1 + bias[c1];
  outp[n*128 + c0] = o0 > 0.f ? o0 : 0.f;
  outp[n*128 + c1] = o1 > 0.f ? o1 : 0.f;
}

// ---------------- layer-2 aggregation: mean over heads, +b2 ----------------
__global__ void k_agg2(const float* __restrict__ h, const float* __restrict__ ew,
                       const int* __restrict__ row_ptr, const int* __restrict__ col,
                       const float* __restrict__ bias, float* __restrict__ outp){
  int gid = blockIdx.x*blockDim.x + threadIdx.x;
  int n = gid >> 6;
  int lane = threadIdx.x & 63;
  if (n >= N_NODES) return;
  int beg = row_ptr[n], end = row_ptr[n+1];
  float acc[8] = {0.f,0.f,0.f,0.f,0.f,0.f,0.f,0.f};
  for (int j = beg; j < end; j++){
    int s = col[j];
    const float4* wp = (const float4*)(ew + (size_t)j*8);
    float4 wa = wp[0], wb = wp[1];
    const float* hr = h + (size_t)s*512;
    acc[0] += wa.x * hr[lane      ];
    acc[1] += wa.y * hr[lane +  64];
    acc[2] += wa.z * hr[lane + 128];
    acc[3] += wa.w * hr[lane + 192];
    acc[4] += wb.x * hr[lane + 256];
    acc[5] += wb.y * hr[lane + 320];
    acc[6] += wb.z * hr[lane + 384];
    acc[7] += wb.w * hr[lane + 448];
  }
  float s8 = ((acc[0]+acc[1])+(acc[2]+acc[3])) + ((acc[4]+acc[5])+(acc[6]+acc[7]));
  outp[n*64 + lane] = s8 * 0.125f + bias[lane];
}

extern "C" void kernel_launch(void* const* d_in, const int* in_sizes, int n_in,
                              void* d_out, int out_size, void* d_ws, size_t ws_size,
                              hipStream_t stream){
  const float* x   = (const float*)d_in[0];
  const int*   ei  = (const int*)d_in[1];
  const float* W1  = (const float*)d_in[2];
  const float* as1 = (const float*)d_in[3];
  const float* ad1 = (const float*)d_in[4];
  const float* b1  = (const float*)d_in[5];
  const float* W2  = (const float*)d_in[6];
  const float* as2 = (const float*)d_in[7];
  const float* ad2 = (const float*)d_in[8];
  const float* b2  = (const float*)d_in[9];
  float* outp = (float*)d_out;

  char* p = (char*)d_ws;
  auto alloc = [&](size_t bytes) -> void* {
    void* r = (void*)p;
    p += (bytes + 255) & ~(size_t)255;
    return r;
  };
  float* h1  = (float*)alloc((size_t)N_NODES*128*4);
  float* hr  = (float*)alloc((size_t)N_NODES*128*4);
  float* h2  = (float*)alloc((size_t)N_NODES*512*4);
  float* als = (float*)alloc((size_t)N_NODES*8*4);
  float* ald = (float*)alloc((size_t)N_NODES*8*4);
  float* ew  = (float*)alloc((size_t)ET*8*4);
  int* row_ptr = (int*)alloc((size_t)(N_NODES+1)*4);
  int* deg  = (int*)alloc((size_t)N_NODES*4);
  int* cnt  = (int*)alloc((size_t)N_NODES*4);
  int* col  = (int*)alloc((size_t)ET*4);
  int* flag = (int*)alloc(256);

  dim3 b256(256);
  // edge-index layout probe + CSR build
  k_detect<<<1, 64, 0, stream>>>(ei, flag);
  k_zero2<<<(N_NODES+255)/256, b256, 0, stream>>>(deg, cnt, N_NODES);
  k_degree<<<(ET+255)/256, b256, 0, stream>>>(ei, deg, flag);
  k_scan<<<1, 1024, 0, stream>>>(deg, row_ptr);
  k_fill<<<(ET+255)/256, b256, 0, stream>>>(ei, row_ptr, cnt, col, flag);

  int nwave_blocks = (N_NODES*64 + 255)/256;   // one wave per node
  // layer 1
  k_gemm_alpha1<<<(N_NODES+7)/8, 128, 0, stream>>>(x, W1, as1, ad1, h1, als, ald);
  k_attn<<<nwave_blocks, b256, 0, stream>>>(als, ald, row_ptr, col, ew);
  k_agg1<<<nwave_blocks, b256, 0, stream>>>(h1, ew, row_ptr, col, b1, hr);
  // layer 2
  k_gemm_alpha2<<<(N_NODES+7)/8, 512, 0, stream>>>(hr, W2, as2, ad2, h2, als, ald);
  k_attn<<<nwave_blocks, b256, 0, stream>>>(als, ald, row_ptr, col, ew);
  k_agg2<<<nwave_blocks, b256, 0, stream>>>(h2, ew, row_ptr, col, b2, outp);
}